// Round 7
// baseline (566.428 us; speedup 1.0000x reference)
//
#include <hip/hip_runtime.h>
#include <hip/hip_bf16.h>

// RNN: B=1024, T=512, H=128, +4 autoregressive steps -> out (1024, 516)
// Round 18: DECOMPOSITION CHANGE. R13/R16/R17 all sit at 153-164us: the
// 8-wave M-split's step floor (~716cy = read-latency + 32xb128 LDS drain +
// barrier) is structural. But the recurrence is embarrassingly parallel in
// BATCH: N-split instead. Each wave owns 16 batch rows + the ENTIRE W in
// registers (128 VGPR) and computes ALL 128 h-units for its rows: next
// step's B-operand is its own C-output. ZERO h-LDS, ZERO barriers, ZERO
// cross-wave traffic. With output-unit permutation
//   O(mt,m) = 32*(mt&3) + 8*(m>>2) + 4*(mt>>2) + (m&3)
// the C fragment at lane (q,n) IS the B fragment the same lane needs next
// step (bfr[kf] = {pk(hv[kf]), pk(hv[kf+4])}) -> repack is free register
// renaming. dec y needs only 2 shfl_xor/step; tail feedback is a register
// copy (xv = y) - pq machinery deleted. 64 independent waves (1024/16),
// 1 per CU. Kept: W/b/w0 pre-scaled by 2*log2e (acc = exp2 argument),
// phase-batched epilogue, fp16 MFMA pipeline, v_cvt_pkrtz packing, fully
// static unrolls (no runtime-indexed arrays -> no scratch).

#define BB 1024
#define TT 512
#define HH 128
#define TOUT 516
#define BM 16          // batch rows per wave (= MFMA N)
#define TWOLOG2E 2.885390082f

typedef __attribute__((ext_vector_type(8))) _Float16 f16x8;
typedef __attribute__((ext_vector_type(4))) float f32x4;
typedef __attribute__((ext_vector_type(4))) unsigned int u32x4;

#define MFMA16(A_, B_, C_) __builtin_amdgcn_mfma_f32_16x16x32_f16(A_, B_, C_, 0, 0, 0)

__global__ void detect_dtype(const void* w, int* flag) {
    const int lane = threadIdx.x;  // 64 threads
    const __hip_bfloat16* p = (const __hip_bfloat16*)w;
    const float v0 = __bfloat162float(p[lane]);
    const float v1 = __bfloat162float(p[64 + lane]);
    const bool bad = !(fabsf(v0) < 100.0f) || !(fabsf(v1) < 100.0f);
    const unsigned long long m = __ballot(bad);
    if (lane == 0) *flag = (__popcll(m) > 4) ? 1 : 0;  // 1 => data is fp32
}

template <bool F32>
__device__ __forceinline__ float ldg(const void* p, int idx) {
    if (F32) return ((const float*)p)[idx];
    return __bfloat162float(((const __hip_bfloat16*)p)[idx]);
}

template <bool F32>
__device__ __forceinline__ void stg(void* p, int idx, float v) {
    if (F32) ((float*)p)[idx] = v;
    else     ((__hip_bfloat16*)p)[idx] = __float2bfloat16(v);
}

// output-unit permutation: row m of M-tile mt computes unit O(mt, m).
// Chosen so C(lane q,n; mt,r) == B-need(lane q,n; kf=mt&3, hi=mt>>2, r):
// unit = 32*kf + 8*q + 4*hi + r for m = 4q+r.
__device__ __forceinline__ int unit_of(int mt, int m) {
    return 32 * (mt & 3) + 8 * (m >> 2) + 4 * (mt >> 2) + (m & 3);
}

template <bool F32>
__device__ void rnn_body(const void* __restrict__ xg, const void* __restrict__ h0,
                         const void* __restrict__ w0, const void* __restrict__ b0,
                         const void* __restrict__ W,  const void* __restrict__ bw,
                         const void* __restrict__ dw, const void* __restrict__ db,
                         void* __restrict__ out, float (*xs)[TT])
{
    const int tid  = threadIdx.x;     // 0..63, single wave per block
    const int q    = tid >> 4;        // 0..3 (k-subchunk / C row-quadrant)
    const int n    = tid & 15;        // batch col (B col / C col / A row)
    const int row0 = blockIdx.x * BM;

    // stage this wave's x rows into LDS (own-wave reads only, no barrier)
    for (int idx = tid; idx < BM * TT; idx += 64) {
        const int rr = idx >> 9, t2 = idx & (TT - 1);
        xs[rr][t2] = ldg<F32>(xg, (row0 + rr) * TT + t2);
    }

    // W fragments for ALL 8 M-tiles (A[m=n][k=32kf+8q+j] = 2log2e *
    // W[unit_of(mt,n)][k]); 128 VGPRs, loaded once.
    f16x8 wa[8][4];
    #pragma unroll
    for (int mt = 0; mt < 8; ++mt) {
        const int row = unit_of(mt, n);
        #pragma unroll
        for (int kf = 0; kf < 4; ++kf) {
            f16x8 fr;
            #pragma unroll
            for (int j = 0; j < 8; ++j)
                fr[j] = (_Float16)(TWOLOG2E * ldg<F32>(W, row * HH + 32 * kf + 8 * q + j));
            wa[mt][kf] = fr;
        }
    }

    // epilogue constants per (mt, r): unit O(mt, 4q+r); pre-scaled
    f32x4 bsum[8], w0v[8], decv[8];
    #pragma unroll
    for (int mt = 0; mt < 8; ++mt) {
        #pragma unroll
        for (int r = 0; r < 4; ++r) {
            const int u = unit_of(mt, 4 * q + r);
            bsum[mt][r] = TWOLOG2E * (ldg<F32>(b0, u) + ldg<F32>(bw, u));
            w0v[mt][r]  = TWOLOG2E * ldg<F32>(w0, u);
            decv[mt][r] = ldg<F32>(dw, u);
        }
    }
    const float dbv = ldg<F32>(db, 0);

    // initial B fragments from h0: bfr[kf] half j = h0[row0+n][32kf+8q+j]
    f16x8 bfr[4];
    #pragma unroll
    for (int kf = 0; kf < 4; ++kf) {
        f16x8 fr;
        #pragma unroll
        for (int j = 0; j < 8; ++j)
            fr[j] = (_Float16)ldg<F32>(h0, (row0 + n) * HH + 32 * kf + 8 * q + j);
        bfr[kf] = fr;
    }

    const int obase = (row0 + n) * TOUT;
    float xv = xs[n][0];

    // acc accumulates 2log2e*z; h = 1 - 2/(exp2(acc)+1)
    #pragma unroll 1
    for (int t = 0; t < TOUT; ++t) {
        // C init: bias + x*w0 (pre-scaled)
        f32x4 acc[8];
        #pragma unroll
        for (int mt = 0; mt < 8; ++mt) {
            #pragma unroll
            for (int r = 0; r < 4; ++r)
                acc[mt][r] = fmaf(xv, w0v[mt][r], bsum[mt][r]);
        }
        // 32 MFMAs: kf outer (8 independent chains of depth 4)
        #pragma unroll
        for (int kf = 0; kf < 4; ++kf) {
            #pragma unroll
            for (int mt = 0; mt < 8; ++mt)
                acc[mt] = MFMA16(wa[mt][kf], bfr[kf], acc[mt]);
        }
        // x prefetch for next step (broadcast read, no conflicts)
        float xnext = 0.0f;
        if (t < 511) xnext = xs[n][t + 1];
        // epilogue, phase-batched (trans ops pipeline)
        f32x4 ex[8], rc[8], hv[8];
        #pragma unroll
        for (int mt = 0; mt < 8; ++mt) {
            #pragma unroll
            for (int r = 0; r < 4; ++r) ex[mt][r] = __builtin_amdgcn_exp2f(acc[mt][r]);
        }
        #pragma unroll
        for (int mt = 0; mt < 8; ++mt) {
            #pragma unroll
            for (int r = 0; r < 4; ++r) rc[mt][r] = __builtin_amdgcn_rcpf(ex[mt][r] + 1.0f);
        }
        #pragma unroll
        for (int mt = 0; mt < 8; ++mt) {
            #pragma unroll
            for (int r = 0; r < 4; ++r) hv[mt][r] = fmaf(-2.0f, rc[mt][r], 1.0f);
        }
        // dec: per-lane partial over this lane's 32 units, then 4-lane reduce
        float p = 0.0f;
        #pragma unroll
        for (int mt = 0; mt < 8; ++mt) {
            #pragma unroll
            for (int r = 0; r < 4; ++r) p = fmaf(decv[mt][r], hv[mt][r], p);
        }
        p += __shfl_xor(p, 16);
        p += __shfl_xor(p, 32);
        const float y = p + dbv;
        if (q == 0) stg<F32>(out, obase + t, y);
        // pack next B (free repack: C fragment == B fragment by unit perm)
        #pragma unroll
        for (int kf = 0; kf < 4; ++kf) {
            u32x4 w;
            w[0] = __builtin_bit_cast(unsigned, __builtin_amdgcn_cvt_pkrtz(hv[kf][0], hv[kf][1]));
            w[1] = __builtin_bit_cast(unsigned, __builtin_amdgcn_cvt_pkrtz(hv[kf][2], hv[kf][3]));
            w[2] = __builtin_bit_cast(unsigned, __builtin_amdgcn_cvt_pkrtz(hv[kf + 4][0], hv[kf + 4][1]));
            w[3] = __builtin_bit_cast(unsigned, __builtin_amdgcn_cvt_pkrtz(hv[kf + 4][2], hv[kf + 4][3]));
            bfr[kf] = __builtin_bit_cast(f16x8, w);
        }
        // next x: sequence input for t<511, own y feedback for the tail
        xv = (t < 511) ? xnext : y;
    }
}

__global__ __launch_bounds__(64, 1)
void rnn_mfma(const void* __restrict__ xg, const void* __restrict__ h0,
              const void* __restrict__ w0, const void* __restrict__ b0,
              const void* __restrict__ W,  const void* __restrict__ bw,
              const void* __restrict__ dw, const void* __restrict__ db,
              void* __restrict__ out, const int* __restrict__ flag)
{
    __shared__ float xs[BM][TT];                            // 32 KB

    const int f = *(volatile const int*)flag;  // block-uniform
    if (f) rnn_body<true >(xg, h0, w0, b0, W, bw, dw, db, out, xs);
    else   rnn_body<false>(xg, h0, w0, b0, W, bw, dw, db, out, xs);
}

extern "C" void kernel_launch(void* const* d_in, const int* in_sizes, int n_in,
                              void* d_out, int out_size, void* d_ws, size_t ws_size,
                              hipStream_t stream) {
    int* flag = (int*)d_ws;
    detect_dtype<<<1, 64, 0, stream>>>(d_in[4], flag);  // probe fc_w
    rnn_mfma<<<BB / BM, 64, 0, stream>>>(d_in[0], d_in[1], d_in[2], d_in[3],
                                         d_in[4], d_in[5], d_in[6], d_in[7],
                                         d_out, flag);
}

// Round 8
// 400.571 us; speedup vs baseline: 1.4141x; 1.4141x over previous
//
#include <hip/hip_runtime.h>
#include <hip/hip_bf16.h>

// RNN: B=1024, T=512, H=128, +4 autoregressive steps -> out (1024, 516)
// Round 19: R18's N-split decomposition was right (batch-parallel, no
// 8-wave LDS drain) but 1 wave needed >=272 persistent VGPRs; the
// allocator capped at 160 and SANK the W loads into the loop (per-step L2
// refetch -> 512us, MfmaUtil 1.3%). Fix: 2 waves per block, M-split in
// half. Each wave: half of W in regs (64 VGPR, ~128-180 persistent total),
// computes 64 units for the block's 16 rows. h-halves exchanged via tiny
// parity-double-buffered LDS (4x ds_write_b64 + 1 barrier + 4x ds_read_b64
// per step vs R13's 32xb128 drain). Unit permutation
//   unit(lmt,m) = 32*lmt + 8*(m>>2) + 4*w + (m&3)
// makes each wave's C fragment exactly its half of next step's B fragment
// (repack = 8 cvt_pkrtz + concat with partner's 8B). Dec y computed
// redundantly in both waves (own 64-unit partial + partner partial via 4B
// LDS on the same barrier) -> tail feedback is a register copy. xs padded
// to 513 (R18 had 16-way conflicts on stride-512). y buffered in LDS,
// flushed at end (no in-loop global stores). Kept: W/b/w0 pre-scaled by
// 2*log2e, phase-batched epilogue, fp16 MFMA, static unrolls everywhere.

#define BB 1024
#define TT 512
#define HH 128
#define TOUT 516
#define BM 16          // batch rows per block (= MFMA N)
#define XSTR 513       // xs stride (dwords) - coprime to 32 banks
#define YSTR 517       // ybuf stride (dwords)
#define TWOLOG2E 2.885390082f

typedef __attribute__((ext_vector_type(8))) _Float16 f16x8;
typedef __attribute__((ext_vector_type(4))) float f32x4;
typedef __attribute__((ext_vector_type(4))) unsigned int u32x4;

#define MFMA16(A_, B_, C_) __builtin_amdgcn_mfma_f32_16x16x32_f16(A_, B_, C_, 0, 0, 0)

__global__ void detect_dtype(const void* w, int* flag) {
    const int lane = threadIdx.x;  // 64 threads
    const __hip_bfloat16* p = (const __hip_bfloat16*)w;
    const float v0 = __bfloat162float(p[lane]);
    const float v1 = __bfloat162float(p[64 + lane]);
    const bool bad = !(fabsf(v0) < 100.0f) || !(fabsf(v1) < 100.0f);
    const unsigned long long m = __ballot(bad);
    if (lane == 0) *flag = (__popcll(m) > 4) ? 1 : 0;  // 1 => data is fp32
}

template <bool F32>
__device__ __forceinline__ float ldg(const void* p, int idx) {
    if (F32) return ((const float*)p)[idx];
    return __bfloat162float(((const __hip_bfloat16*)p)[idx]);
}

template <bool F32>
__device__ void rnn_body(const void* __restrict__ xg, const void* __restrict__ h0,
                         const void* __restrict__ w0, const void* __restrict__ b0,
                         const void* __restrict__ W,  const void* __restrict__ bw,
                         const void* __restrict__ dw, const void* __restrict__ db,
                         void* __restrict__ out,
                         float (*xs)[XSTR], float (*ybuf)[YSTR],
                         uint2 (*hx)[2][4][64], float (*pd)[2][16])
{
    const int tid  = threadIdx.x;     // 0..127
    const int lane = tid & 63;
    const int w    = tid >> 6;        // 0,1: which M-half this wave owns
    const int q    = lane >> 4;       // 0..3
    const int n    = lane & 15;       // batch col (B col / C col / A row)
    const int row0 = blockIdx.x * BM;

    // stage x rows (fp32, padded stride)
    for (int idx = tid; idx < BM * TT; idx += 128) {
        const int rr = idx >> 9, t2 = idx & (TT - 1);
        xs[rr][t2] = ldg<F32>(xg, (row0 + rr) * TT + t2);
    }

    // W fragments for this wave's 4 local M-tiles.
    // A[m=n][k=32kf+8q+j] for tile lmt -> W row unit(lmt, n), PRE-SCALED.
    f16x8 wa[4][4];
    #pragma unroll
    for (int lmt = 0; lmt < 4; ++lmt) {
        const int row = 32 * lmt + 8 * (n >> 2) + 4 * w + (n & 3);
        #pragma unroll
        for (int kf = 0; kf < 4; ++kf) {
            f16x8 fr;
            #pragma unroll
            for (int j = 0; j < 8; ++j)
                fr[j] = (_Float16)(TWOLOG2E * ldg<F32>(W, row * HH + 32 * kf + 8 * q + j));
            wa[lmt][kf] = fr;
        }
    }

    // epilogue constants per (lmt, r): C row m=4q+r -> unit 32lmt+8q+4w+r
    f32x4 bsum[4], w0v[4], decv[4];
    #pragma unroll
    for (int lmt = 0; lmt < 4; ++lmt) {
        #pragma unroll
        for (int r = 0; r < 4; ++r) {
            const int u = 32 * lmt + 8 * q + 4 * w + r;
            bsum[lmt][r] = TWOLOG2E * (ldg<F32>(b0, u) + ldg<F32>(bw, u));
            w0v[lmt][r]  = TWOLOG2E * ldg<F32>(w0, u);
            decv[lmt][r] = ldg<F32>(dw, u);
        }
    }
    const float dbv = ldg<F32>(db, 0);

    // initial B fragments from h0: bfr[kf][j] = h0[row0+n][32kf+8q+j]
    f16x8 bfr[4];
    #pragma unroll
    for (int kf = 0; kf < 4; ++kf) {
        f16x8 fr;
        #pragma unroll
        for (int j = 0; j < 8; ++j)
            fr[j] = (_Float16)ldg<F32>(h0, (row0 + n) * HH + 32 * kf + 8 * q + j);
        bfr[kf] = fr;
    }

    __syncthreads();

    float xv = xs[n][0];

    // acc accumulates 2log2e*z; h = 1 - 2/(exp2(acc)+1)
    #pragma unroll 1
    for (int t = 0; t < TOUT; ++t) {
        const int par = t & 1;
        // C init: bias + x*w0 (pre-scaled)
        f32x4 acc[4];
        #pragma unroll
        for (int lmt = 0; lmt < 4; ++lmt) {
            #pragma unroll
            for (int r = 0; r < 4; ++r)
                acc[lmt][r] = fmaf(xv, w0v[lmt][r], bsum[lmt][r]);
        }
        // 16 MFMAs: 4 independent chains (lmt) of depth 4 (kf)
        #pragma unroll
        for (int kf = 0; kf < 4; ++kf) {
            #pragma unroll
            for (int lmt = 0; lmt < 4; ++lmt)
                acc[lmt] = MFMA16(wa[lmt][kf], bfr[kf], acc[lmt]);
        }
        // x prefetch (conflict-free: stride 513)
        float xnext = 0.0f;
        if (t < 511) xnext = xs[n][t + 1];
        // epilogue, phase-batched
        f32x4 ex[4], rc[4], hv[4];
        #pragma unroll
        for (int lmt = 0; lmt < 4; ++lmt) {
            #pragma unroll
            for (int r = 0; r < 4; ++r) ex[lmt][r] = __builtin_amdgcn_exp2f(acc[lmt][r]);
        }
        #pragma unroll
        for (int lmt = 0; lmt < 4; ++lmt) {
            #pragma unroll
            for (int r = 0; r < 4; ++r) rc[lmt][r] = __builtin_amdgcn_rcpf(ex[lmt][r] + 1.0f);
        }
        #pragma unroll
        for (int lmt = 0; lmt < 4; ++lmt) {
            #pragma unroll
            for (int r = 0; r < 4; ++r) hv[lmt][r] = fmaf(-2.0f, rc[lmt][r], 1.0f);
        }
        // dec partial over this wave's 64 units, reduced over q
        float p = 0.0f;
        #pragma unroll
        for (int lmt = 0; lmt < 4; ++lmt) {
            #pragma unroll
            for (int r = 0; r < 4; ++r) p = fmaf(decv[lmt][r], hv[lmt][r], p);
        }
        p += __shfl_xor(p, 16);
        p += __shfl_xor(p, 32);
        // pack own h-half (C frag == B-half by unit perm) + exchange
        uint2 own[4];
        #pragma unroll
        for (int kf = 0; kf < 4; ++kf) {
            own[kf].x = __builtin_bit_cast(unsigned, __builtin_amdgcn_cvt_pkrtz(hv[kf][0], hv[kf][1]));
            own[kf].y = __builtin_bit_cast(unsigned, __builtin_amdgcn_cvt_pkrtz(hv[kf][2], hv[kf][3]));
            hx[par][w][kf][lane] = own[kf];   // ds_write_b64, 2-way = free
        }
        if (q == 0) pd[par][w][n] = p;
        __syncthreads();
        // y (both waves, redundant): own partial + partner partial
        const float ycur = p + pd[par][1 - w][n] + dbv;
        if (w == 0 && q == 0) ybuf[n][t] = ycur;
        // assemble next B: low 8B = wave0 half (units +0..3), high = wave1
        #pragma unroll
        for (int kf = 0; kf < 4; ++kf) {
            const uint2 oth = hx[par][1 - w][kf][lane];
            u32x4 bb;
            if (w == 0) { bb[0] = own[kf].x; bb[1] = own[kf].y; bb[2] = oth.x; bb[3] = oth.y; }
            else        { bb[0] = oth.x;     bb[1] = oth.y;     bb[2] = own[kf].x; bb[3] = own[kf].y; }
            bfr[kf] = __builtin_bit_cast(f16x8, bb);
        }
        // next x: sequence input for t<511, own y feedback for the tail
        xv = (t < 511) ? xnext : ycur;
    }
    __syncthreads();

    // flush outputs (coalesced over t)
    for (int rr = 0; rr < BM; ++rr)
        for (int t2 = tid; t2 < TOUT; t2 += 128) {
            const int o = (row0 + rr) * TOUT + t2;
            const float y = ybuf[rr][t2];
            if (F32) ((float*)out)[o] = y;
            else     ((__hip_bfloat16*)out)[o] = __float2bfloat16(y);
        }
}

__global__ __launch_bounds__(128, 1)
void rnn_mfma(const void* __restrict__ xg, const void* __restrict__ h0,
              const void* __restrict__ w0, const void* __restrict__ b0,
              const void* __restrict__ W,  const void* __restrict__ bw,
              const void* __restrict__ dw, const void* __restrict__ db,
              void* __restrict__ out, const int* __restrict__ flag)
{
    __shared__ float xs[BM][XSTR];                          // 32.8 KB
    __shared__ float ybuf[BM][YSTR];                        // 33.1 KB
    __shared__ __align__(16) uint2 hx[2][2][4][64];         // 8 KB [par][w][kf][lane]
    __shared__ float pd[2][2][16];                          // 256 B [par][w][n]

    const int f = *(volatile const int*)flag;  // block-uniform
    if (f) rnn_body<true >(xg, h0, w0, b0, W, bw, dw, db, out, xs, ybuf, hx, pd);
    else   rnn_body<false>(xg, h0, w0, b0, W, bw, dw, db, out, xs, ybuf, hx, pd);
}

extern "C" void kernel_launch(void* const* d_in, const int* in_sizes, int n_in,
                              void* d_out, int out_size, void* d_ws, size_t ws_size,
                              hipStream_t stream) {
    int* flag = (int*)d_ws;
    detect_dtype<<<1, 64, 0, stream>>>(d_in[4], flag);  // probe fc_w
    rnn_mfma<<<BB / BM, 128, 0, stream>>>(d_in[0], d_in[1], d_in[2], d_in[3],
                                          d_in[4], d_in[5], d_in[6], d_in[7],
                                          d_out, flag);
}